// Round 14
// baseline (2061.362 us; speedup 1.0000x reference)
//
#include <hip/hip_runtime.h>
#include <hip/hip_bf16.h>
#include <cstdint>
#include <cstddef>
#include <cmath>

typedef __bf16 bf16;
typedef bf16 bf16x8 __attribute__((ext_vector_type(8)));
typedef float f32x4 __attribute__((ext_vector_type(4)));

#define D_DIM 128
#define NB 32      // nodes per tile (node kernels)
#define EB 128     // edges per tile (edge kernel)
#define TS 136     // LDS stride for 128-wide bf16 tiles (+8 pad)
#define XS 264     // LDS stride for 256-wide bf16 tile (+8 pad)
#define SRS 132    // LDS stride for 128-wide f32 sred tile
#define AS 392     // LDS stride for 384-wide node-A input tile

__device__ __forceinline__ f32x4 mfma16(bf16x8 a, bf16x8 b, f32x4 c) {
  return __builtin_amdgcn_mfma_f32_16x16x32_bf16(a, b, c, 0, 0, 0);
}

__device__ __forceinline__ int clampi(int v, int hi) {
  return v < 0 ? 0 : (v > hi ? hi : v);
}

// stage 16 consecutive f32 (64B, aligned) -> 16 bf16 in LDS
__device__ __forceinline__ void stage16(const float* __restrict__ src, bf16* dst) {
  bf16 tmp[16];
#pragma unroll
  for (int q = 0; q < 4; ++q) {
    f32x4 f = ((const f32x4*)src)[q];
#pragma unroll
    for (int j = 0; j < 4; ++j) tmp[q * 4 + j] = (bf16)f[j];
  }
  *(bf16x8*)dst = *(bf16x8*)tmp;
  *(bf16x8*)(dst + 8) = *(bf16x8*)(tmp + 8);
}

// ---- layer1 compute (node kernels): A[32 x K] from LDS segments @ W1t[256 x K]^T -> acc
template <int NSEG>
__device__ __forceinline__ void mlp_layer1_compute(const bf16* s0, const bf16* s1,
                                                   const bf16* s2, const int S,
                                                   const bf16* __restrict__ W1t,
                                                   f32x4 acc[2][4],
                                                   const int lane, const int w) {
  const int col = lane & 15, quad = lane >> 4;
  const int K = NSEG * 128;
  const bf16* segs[3] = {s0, s1, s2};
#pragma unroll
  for (int sg = 0; sg < NSEG; ++sg) {
    const bf16* xl = segs[sg];
#pragma unroll
    for (int kk = 0; kk < 128; kk += 32) {
      const int k0 = sg * 128 + kk;
      bf16x8 a0 = *(const bf16x8*)&xl[col * S + kk + quad * 8];
      bf16x8 a1 = *(const bf16x8*)&xl[(col + 16) * S + kk + quad * 8];
#pragma unroll
      for (int nt = 0; nt < 4; ++nt) {
        bf16x8 b = *(const bf16x8*)(W1t + (size_t)(w * 64 + nt * 16 + col) * K + k0 + quad * 8);
        acc[0][nt] = mfma16(a0, b, acc[0][nt]);
        acc[1][nt] = mfma16(a1, b, acc[1][nt]);
      }
    }
  }
}

// ---- layer1 store: bias + relu -> x2 (stride XS). Call AFTER a barrier if x2 aliases x.
__device__ __forceinline__ void mlp_layer1_store(f32x4 acc[2][4],
                                                 const float* __restrict__ B1,
                                                 bf16* x2, const int lane, const int w) {
  const int col = lane & 15, quad = lane >> 4;
#pragma unroll
  for (int nt = 0; nt < 4; ++nt) {
    const int n = w * 64 + nt * 16 + col;
    const float b1 = B1[n];
#pragma unroll
    for (int mt = 0; mt < 2; ++mt)
#pragma unroll
      for (int i = 0; i < 4; ++i) {
        float v = acc[mt][nt][i] + b1;
        x2[(mt * 16 + quad * 4 + i) * XS + n] = (bf16)(v > 0.f ? v : 0.f);
      }
  }
}

// ---- layer2: x2[32 x 256] @ W2t[128 x 256]^T -> acc2
__device__ __forceinline__ void mlp_layer2(const bf16* x2, const bf16* __restrict__ W2t,
                                           const int lane, const int w, f32x4 acc2[2][2]) {
  const int col = lane & 15, quad = lane >> 4;
#pragma unroll
  for (int k0 = 0; k0 < 256; k0 += 32) {
    bf16x8 a0 = *(const bf16x8*)&x2[col * XS + k0 + quad * 8];
    bf16x8 a1 = *(const bf16x8*)&x2[(col + 16) * XS + k0 + quad * 8];
#pragma unroll
    for (int nt = 0; nt < 2; ++nt) {
      bf16x8 b = *(const bf16x8*)(W2t + (size_t)(w * 32 + nt * 16 + col) * 256 + k0 + quad * 8);
      acc2[0][nt] = mfma16(a0, b, acc2[0][nt]);
      acc2[1][nt] = mfma16(a1, b, acc2[1][nt]);
    }
  }
}

// ---- Z emission: Z[w] = x(bf16 h tile, stride S) @ W1-slice, w in {P-oth,P-own,C-oth,C-own}
__device__ __forceinline__ void emit_z(const bf16* x, const int S,
                                       const bf16* __restrict__ Pw1t,
                                       const bf16* __restrict__ Cw1t,
                                       bf16* __restrict__ Zbuf,
                                       const int r0, const int N,
                                       const int lane, const int w) {
  const int col = lane & 15, quad = lane >> 4;
  const bf16* base = ((w & 2) ? Cw1t : Pw1t) + (w & 1) * 128;  // k-offset slice, row-stride 384
  bf16* out = Zbuf + (size_t)w * ((size_t)N * 256);
#pragma unroll
  for (int half = 0; half < 2; ++half) {
    f32x4 acc[2][8] = {};
#pragma unroll
    for (int kc = 0; kc < 4; ++kc) {
      bf16x8 a0 = *(const bf16x8*)&x[col * S + kc * 32 + quad * 8];
      bf16x8 a1 = *(const bf16x8*)&x[(col + 16) * S + kc * 32 + quad * 8];
#pragma unroll
      for (int nt = 0; nt < 8; ++nt) {
        const int n = half * 128 + nt * 16 + col;
        bf16x8 b = *(const bf16x8*)(base + (size_t)n * 384 + kc * 32 + quad * 8);
        acc[0][nt] = mfma16(a0, b, acc[0][nt]);
        acc[1][nt] = mfma16(a1, b, acc[1][nt]);
      }
    }
#pragma unroll
    for (int nt = 0; nt < 8; ++nt) {
      const int n = half * 128 + nt * 16 + col;
#pragma unroll
      for (int mt = 0; mt < 2; ++mt)
#pragma unroll
        for (int i = 0; i < 4; ++i) {
          int g = r0 + mt * 16 + quad * 4 + i;
          if (g < N) out[(size_t)g * 256 + n] = (bf16)acc[mt][nt][i];
        }
    }
  }
}

// ---------------- small utility kernels ----------------

// f32 [K,N] -> bf16 [N,K]
__global__ void transpose_kernel(const float* __restrict__ in, bf16* __restrict__ out,
                                 int K, int N) {
  int k = blockIdx.x * blockDim.x + threadIdx.x;
  int n = blockIdx.y;
  if (k < K) out[(size_t)n * K + k] = (bf16)in[(size_t)k * N + n];
}

__global__ void count_kernel(const int* __restrict__ epn, const int* __restrict__ ecn,
                             int* cntp, int* cntc, int E, int N) {
  int i = blockIdx.x * blockDim.x + threadIdx.x;
  if (i < E) {
    atomicAdd(&cntp[clampi(epn[i], N - 1)], 1);
    atomicAdd(&cntc[clampi(ecn[i], N - 1)], 1);
  }
}

__global__ void inv_kernel(const int* __restrict__ cntp, const int* __restrict__ cntc,
                           float* invp, float* invc, int N) {
  int i = blockIdx.x * blockDim.x + threadIdx.x;
  if (i < N) {
    invp[i] = 1.f / fmaxf((float)cntp[i], 1.f);
    invc[i] = 1.f / fmaxf((float)cntc[i], 1.f);
  }
}

// exclusive scan; blockIdx.x selects (cntp->offp) or (cntc->offc), both run in parallel
__global__ void scan_pair_kernel(const int* __restrict__ cntp, const int* __restrict__ cntc,
                                 int* __restrict__ offp, int* __restrict__ offc, int n) {
  const int* cnt = blockIdx.x ? cntc : cntp;
  int* offs = blockIdx.x ? offc : offp;
  __shared__ int buf[1024];
  __shared__ int carry;
  const int t = threadIdx.x;
  if (t == 0) carry = 0;
  __syncthreads();
  for (int base = 0; base < n; base += 1024) {
    int v = (base + t < n) ? cnt[base + t] : 0;
    buf[t] = v;
    __syncthreads();
    for (int d = 1; d < 1024; d <<= 1) {
      int add = (t >= d) ? buf[t - d] : 0;
      __syncthreads();
      buf[t] += add;
      __syncthreads();
    }
    if (base + t < n) offs[base + t] = carry + buf[t] - v;  // exclusive
    __syncthreads();
    if (t == 1023) carry += buf[1023];
    __syncthreads();
  }
}

// counting-sort scatter: emit per-side (own, oth, x) directly in SORTED edge order,
// removing the 2-deep index-gather chain from every edge-kernel tile.
__global__ void scatter_kernel(const int* __restrict__ epn, const int* __restrict__ ecn,
                               const float* __restrict__ epi, const float* __restrict__ eci,
                               const int* __restrict__ offp, const int* __restrict__ offc,
                               int* curp, int* curc,
                               int* ownp_s, int* othp_s, float* xp_s,
                               int* ownc_s, int* othc_s, float* xc_s, int E, int N) {
  int i = blockIdx.x * blockDim.x + threadIdx.x;
  if (i < E) {
    int p = clampi(epn[i], N - 1);
    int c = clampi(ecn[i], N - 1);
    int pp = offp[p] + atomicAdd(&curp[p], 1);
    ownp_s[pp] = p; othp_s[pp] = c; xp_s[pp] = epi[i];
    int pc = offc[c] + atomicAdd(&curc[c], 1);
    ownc_s[pc] = c; othc_s[pc] = p; xc_s[pc] = eci[i];
  }
}

// ---------------- one-time E-MLP collapse: piecewise-affine tables (parallel) ----------------
// feat(x) = relu(Ew2^T relu(x*Ew1+Eb1) + Eb2) is piecewise-linear in scalar x with
// breakpoints t_k = -Eb1[k]/Ew1[k]. Within segment s: feat_pre = x*Atab[s] + Btab[s].
// Grid: 128 blocks (one output column each) x 256 threads (one hidden unit each).

__global__ __launch_bounds__(256) void emlp_table_kernel(
    const float* __restrict__ Ew1, const float* __restrict__ Eb1,
    const float* __restrict__ Ew2, const float* __restrict__ Eb2,
    float* __restrict__ ts_out, float* __restrict__ Atab, float* __restrict__ Btab) {
  __shared__ float s_tk[256], s_w[256], s_b[256];
  __shared__ int s_k[256];
  __shared__ float sA[256], sB[256];
  const int j = blockIdx.x;  // column 0..127
  const int t = threadIdx.x;
  float w = Ew1[t], b = Eb1[t];
  float tk = (w != 0.f) ? (-b / w) : INFINITY;  // w==0: never toggles
  s_tk[t] = tk; s_w[t] = w; s_b[t] = b;
  __syncthreads();
  // rank sort (ties broken by index)
  int rank = 0;
  for (int u = 0; u < 256; ++u) {
    float tu = s_tk[u];
    if (tu < tk || (tu == tk && u < t)) ++rank;
  }
  s_k[rank] = t;
  if (j == 0) ts_out[rank] = tk;
  // base segment (x -> -inf): unit active iff w<0, or w==0 && b>0
  float w2own = Ew2[(size_t)t * 128 + j];
  bool act = (w < 0.f || (w == 0.f && b > 0.f));
  sA[t] = act ? w * w2own : 0.f;
  sB[t] = act ? b * w2own : 0.f;
  __syncthreads();
  for (int d = 128; d > 0; d >>= 1) {
    if (t < d) { sA[t] += sA[t + d]; sB[t] += sB[t + d]; }
    __syncthreads();
  }
  const float baseA = sA[0], baseB = sB[0];
  __syncthreads();
  // per-sorted-position delta (crossing upward: w>0 activates, w<0 deactivates)
  int k = s_k[t];
  float wk = s_w[k], bk = s_b[k];
  float dA = 0.f, dB = 0.f;
  if (wk != 0.f) {
    float w2 = Ew2[(size_t)k * 128 + j];
    float sgn = wk > 0.f ? 1.f : -1.f;
    dA = sgn * wk * w2;
    dB = sgn * bk * w2;
  }
  sA[t] = dA; sB[t] = dB;
  __syncthreads();
  // inclusive Hillis-Steele scan
  for (int d = 1; d < 256; d <<= 1) {
    float aA = (t >= d) ? sA[t - d] : 0.f;
    float aB = (t >= d) ? sB[t - d] : 0.f;
    __syncthreads();
    sA[t] += aA; sB[t] += aB;
    __syncthreads();
  }
  const float eb2 = Eb2[j];
  if (t == 0) { Atab[j] = baseA; Btab[j] = baseB + eb2; }
  Atab[(size_t)(t + 1) * 128 + j] = baseA + sA[t];
  Btab[(size_t)(t + 1) * 128 + j] = baseB + sB[t] + eb2;
}

// ---------------- MLP_V + Z-emission: h = mlp(batch_token); Z = h @ W1-slices ----------------
// x2 and the h tile alias the x staging buffer (layer1 split compute/store with a
// barrier between) -> LDS 25.6 -> 16.9 KB, 4 blocks/CU.

__global__ __launch_bounds__(256, 4) void node_v_kernel(
    const float* __restrict__ bt, const bf16* __restrict__ W1t, const float* __restrict__ B1,
    const bf16* __restrict__ W2t, const float* __restrict__ B2,
    const bf16* __restrict__ Pw1t, const bf16* __restrict__ Cw1t,
    bf16* __restrict__ Zbuf, float* __restrict__ hout, int N) {
  __shared__ __attribute__((aligned(16))) char ubuf[NB * XS * 2];  // 16896 B
  bf16* x = (bf16*)ubuf;   // staged input, stride TS (8704 B)
  bf16* x2 = (bf16*)ubuf;  // after layer1, stride XS
  bf16* xh = (bf16*)ubuf;  // h tile for emit_z, stride TS
  const int t = threadIdx.x;
  const int r0 = blockIdx.x * NB;
  {
    const int r = t >> 3, c0 = (t & 7) * 16;
    int g = r0 + r; if (g >= N) g = N - 1;
    stage16(bt + (size_t)g * D_DIM + c0, &x[r * TS + c0]);
  }
  __syncthreads();
  const int lane = t & 63, w = t >> 6, col = lane & 15, quad = lane >> 4;
  f32x4 acc1[2][4] = {};
  mlp_layer1_compute<1>(x, x, x, TS, W1t, acc1, lane, w);
  __syncthreads();  // all x reads done; x2 may overwrite
  mlp_layer1_store(acc1, B1, x2, lane, w);
  __syncthreads();
  f32x4 acc2[2][2] = {};
  mlp_layer2(x2, W2t, lane, w, acc2);
  __syncthreads();  // x2 reads done; xh may overwrite
#pragma unroll
  for (int nt = 0; nt < 2; ++nt) {
    const int n = w * 32 + nt * 16 + col;
    const float b2 = B2[n];
#pragma unroll
    for (int mt = 0; mt < 2; ++mt)
#pragma unroll
      for (int i = 0; i < 4; ++i) {
        int m = mt * 16 + quad * 4 + i;
        int g = r0 + m;
        float v = acc2[mt][nt][i] + b2;
        v = v > 0.f ? v : 0.f;
        xh[m * TS + n] = (bf16)v;  // h tile for Z emission
        if (g < N) hout[(size_t)g * D_DIM + n] = v;
      }
  }
  __syncthreads();  // h tile ready
  emit_z(xh, TS, Pw1t, Cw1t, Zbuf, r0, N, lane, w);
}

// ---------------- per-hop edge kernel: EB=128, 1024 threads (16 waves), 2 blocks/CU ----
// z(e) = relu(ZO[oth(e)] + ZW[own(e)] + feat(x_e)@W1c + b1) ; out = z @ W2 ; segsum by own.
// Edge metadata pre-sorted (own/oth/x arrays) -> 3 coalesced loads, no gather chain.

__global__ __launch_bounds__(1024, 8) void edge_side_kernel(
    const bf16* __restrict__ Zbuf,
    const int* __restrict__ ownp_s, const int* __restrict__ othp_s,
    const float* __restrict__ xp_s,
    const int* __restrict__ ownc_s, const int* __restrict__ othc_s,
    const float* __restrict__ xc_s,
    const float* __restrict__ ets, const float* __restrict__ Atab,
    const float* __restrict__ Btab,
    const bf16* __restrict__ Pw1t, const float* __restrict__ Pb1,
    const bf16* __restrict__ Pw2t, const float* __restrict__ Pb2,
    const bf16* __restrict__ Cw1t, const float* __restrict__ Cb1,
    const bf16* __restrict__ Cw2t, const float* __restrict__ Cb2,
    float* __restrict__ accp, float* __restrict__ accc, int E, int N) {
  const int side = blockIdx.y;  // wave-uniform
  const size_t NZ = (size_t)N * 256;
  const bf16* ZO     = Zbuf + (size_t)(side * 2 + 0) * NZ;
  const bf16* ZW     = Zbuf + (size_t)(side * 2 + 1) * NZ;
  const int* owns    = side ? ownc_s : ownp_s;
  const int* oths    = side ? othc_s : othp_s;
  const float* xs    = side ? xc_s : xp_s;
  const bf16* W1c    = (side ? Cw1t : Pw1t) + 256;  // ep-slice, row-stride 384
  const float* B1    = side ? Cb1 : Pb1;
  const bf16* W2t    = side ? Cw2t : Pw2t;
  const float* B2    = side ? Cb2 : Pb2;
  float* acc         = side ? accc : accp;

  __shared__ int s_own[EB], s_oth[EB];  // s_own doubles as segment key; -1 = pad
  __shared__ float s_x[EB];
  __shared__ float s_ts[256];  // sorted breakpoints
  // union buffer: [feat 128x136 bf16 | xzh 128x136 bf16] ; sred 128x132 f32 aliases both
  __shared__ __attribute__((aligned(16))) char ubuf[EB * TS * 2 * 2];  // 69632 B
  bf16* feat = (bf16*)ubuf;
  bf16* xzh  = (bf16*)(ubuf + EB * TS * 2);
  float* sred = (float*)ubuf;  // 128*132*4 = 67584 <= 69632

  const int t = threadIdx.x;
  const int e0 = blockIdx.x * EB;
  if (t < 256) s_ts[t] = ets[t];
  if (t < EB) {
    int e = e0 + t;
    if (e < E) {
      s_own[t] = owns[e];
      s_oth[t] = oths[e];
      s_x[t] = xs[e];
    } else {
      s_own[t] = -1; s_oth[t] = 0; s_x[t] = 0.f;
    }
  }
  __syncthreads();  // b0: indices + breakpoints ready

  const int lane = t & 63, w = t >> 6, col = lane & 15, quad = lane >> 4;
  const int zr = t >> 3, zc = (t & 7) * 16;  // 8 threads/row, 16 cols each (per half)

  // ---- issue ZO half-0 gather EARLY (row pointers kept for later phases)
  const bf16* zo_row;
  const bf16* zw_row;
  bf16x8 va[2];
  {
    int ro = s_oth[zr];
    int rw = s_own[zr]; if (rw < 0) rw = 0;
    zo_row = ZO + (size_t)ro * 256;
    zw_row = ZW + (size_t)rw * 256;
#pragma unroll
    for (int q = 0; q < 2; ++q) va[q] = *(const bf16x8*)(zo_row + zc + q * 8);
  }

  // ---- feat via segment-affine tables (8 threads/edge, 16 cols; hides gather latency)
  {
    const float xv = s_x[zr];
    int lo = 0, hi = 256;
#pragma unroll
    for (int it = 0; it < 8; ++it) {
      int mid = (lo + hi) >> 1;
      if (s_ts[mid] < xv) lo = mid + 1; else hi = mid;
    }
    const float* Ar = Atab + (size_t)lo * 128 + zc;
    const float* Br = Btab + (size_t)lo * 128 + zc;
#pragma unroll
    for (int q = 0; q < 2; ++q) {
      f32x4 a0 = *(const f32x4*)(Ar + q * 8);
      f32x4 a1 = *(const f32x4*)(Ar + q * 8 + 4);
      f32x4 b0 = *(const f32x4*)(Br + q * 8);
      f32x4 b1v = *(const f32x4*)(Br + q * 8 + 4);
      bf16 o[8];
#pragma unroll
      for (int j = 0; j < 4; ++j) {
        float v0 = fmaf(xv, a0[j], b0[j]);
        float v1 = fmaf(xv, a1[j], b1v[j]);
        o[j] = (bf16)(v0 > 0.f ? v0 : 0.f);
        o[4 + j] = (bf16)(v1 > 0.f ? v1 : 0.f);
      }
      *(bf16x8*)&feat[zr * TS + zc + q * 8] = *(bf16x8*)o;
    }
  }

  // ---- zsum half-0 (va landed; ZW rows sort-clustered, L2-hot)
  {
#pragma unroll
    for (int q = 0; q < 2; ++q) {
      bf16x8 b = *(const bf16x8*)(zw_row + zc + q * 8);
      bf16 o[8];
#pragma unroll
      for (int j = 0; j < 8; ++j) o[j] = (bf16)((float)va[q][j] + (float)b[j]);
      *(bf16x8*)&xzh[zr * TS + zc + q * 8] = *(bf16x8*)o;
    }
  }
  __syncthreads();  // b1: feat + xzh(h0 zsum) ready

  // ---- issue ZO half-1 gather (covered by W1c + layer2 of half 0)
#pragma unroll
  for (int q = 0; q < 2; ++q) va[q] = *(const bf16x8*)(zo_row + 128 + zc + q * 8);

  f32x4 acc2[4];
#pragma unroll
  for (int g = 0; g < 4; ++g) acc2[g] = (f32x4){0.f, 0.f, 0.f, 0.f};

  const int nh = (w & 7) * 16 + col;  // wave's column within the current 128-wide half
  const int rbase = (w >> 3) * 64;    // wave's row-half of the 128-edge tile

  // ---- half 0: W1c GEMM + fused z-add + relu (in place), then layer2 partial
  {
    f32x4 acc1[4] = {};
#pragma unroll
    for (int kc = 0; kc < 4; ++kc) {
      bf16x8 b = *(const bf16x8*)(W1c + (size_t)nh * 384 + kc * 32 + quad * 8);
#pragma unroll
      for (int g = 0; g < 4; ++g) {
        bf16x8 afr = *(const bf16x8*)&feat[(rbase + g * 16 + col) * TS + kc * 32 + quad * 8];
        acc1[g] = mfma16(afr, b, acc1[g]);
      }
    }
    const float b1v = B1[nh];
#pragma unroll
    for (int g = 0; g < 4; ++g)
#pragma unroll
      for (int i = 0; i < 4; ++i) {
        const int m = rbase + g * 16 + quad * 4 + i;
        float v = acc1[g][i] + b1v + (float)xzh[m * TS + nh];
        xzh[m * TS + nh] = (bf16)(v > 0.f ? v : 0.f);
      }
  }
  __syncthreads();  // b2: xzh = relu(z h0) ready
#pragma unroll
  for (int kc = 0; kc < 4; ++kc) {
    bf16x8 b = *(const bf16x8*)(W2t + (size_t)nh * 256 + kc * 32 + quad * 8);
#pragma unroll
    for (int g = 0; g < 4; ++g) {
      bf16x8 afr = *(const bf16x8*)&xzh[(rbase + g * 16 + col) * TS + kc * 32 + quad * 8];
      acc2[g] = mfma16(afr, b, acc2[g]);
    }
  }
  __syncthreads();  // b3: xzh(h0) reads done

  // ---- zsum half-1
  {
#pragma unroll
    for (int q = 0; q < 2; ++q) {
      bf16x8 b = *(const bf16x8*)(zw_row + 128 + zc + q * 8);
      bf16 o[8];
#pragma unroll
      for (int j = 0; j < 8; ++j) o[j] = (bf16)((float)va[q][j] + (float)b[j]);
      *(bf16x8*)&xzh[zr * TS + zc + q * 8] = *(bf16x8*)o;
    }
  }
  __syncthreads();  // b4: xzh(h1 zsum) ready

  // ---- half 1: W1c GEMM + fused z-add + relu, then layer2 partial (k offset 128)
  {
    f32x4 acc1[4] = {};
#pragma unroll
    for (int kc = 0; kc < 4; ++kc) {
      bf16x8 b = *(const bf16x8*)(W1c + (size_t)(128 + nh) * 384 + kc * 32 + quad * 8);
#pragma unroll
      for (int g = 0; g < 4; ++g) {
        bf16x8 afr = *(const bf16x8*)&feat[(rbase + g * 16 + col) * TS + kc * 32 + quad * 8];
        acc1[g] = mfma16(afr, b, acc1[g]);
      }
    }
    const float b1v = B1[128 + nh];
#pragma unroll
    for (int g = 0; g < 4; ++g)
#pragma unroll
      for (int i = 0; i < 4; ++i) {
        const int m = rbase + g * 16 + quad * 4 + i;
        float v = acc1[g][i] + b1v + (float)xzh[m * TS + nh];
        xzh[m * TS + nh] = (bf16)(v > 0.f ? v : 0.f);
      }
  }
  __syncthreads();  // b5: xzh = relu(z h1) ready
#pragma unroll
  for (int kc = 0; kc < 4; ++kc) {
    bf16x8 b = *(const bf16x8*)(W2t + (size_t)nh * 256 + 128 + kc * 32 + quad * 8);
#pragma unroll
    for (int g = 0; g < 4; ++g) {
      bf16x8 afr = *(const bf16x8*)&xzh[(rbase + g * 16 + col) * TS + kc * 32 + quad * 8];
      acc2[g] = mfma16(afr, b, acc2[g]);
    }
  }
  __syncthreads();  // b6: xzh + feat dead; sred may overwrite

  // ---- sred write (wave-private cols x row-half) + segmented reduce + atomics
  {
    const float b2 = B2[nh];
#pragma unroll
    for (int g = 0; g < 4; ++g)
#pragma unroll
      for (int i = 0; i < 4; ++i) {
        float v = acc2[g][i] + b2;
        sred[(rbase + g * 16 + quad * 4 + i) * SRS + nh] = v > 0.f ? v : 0.f;
      }
  }
  __syncthreads();  // b7: sred fully written
  {
    const int c = t & 127;          // column
    const int rlo = (t >> 7) * 16;  // 8 segments of 16 rows
    float run = 0.f;
    int cur = s_own[rlo];
    for (int r = rlo; r < rlo + 16; ++r) {
      int k = s_own[r];
      if (k != cur) {
        if (cur >= 0)
          __hip_atomic_fetch_add(&acc[(size_t)cur * D_DIM + c], run,
                                 __ATOMIC_RELAXED, __HIP_MEMORY_SCOPE_AGENT);
        run = 0.f;
        cur = k;
      }
      run += sred[r * SRS + c];
    }
    if (cur >= 0)
      __hip_atomic_fetch_add(&acc[(size_t)cur * D_DIM + c], run,
                             __ATOMIC_RELAXED, __HIP_MEMORY_SCOPE_AGENT);
  }
}

// ---------------- per-hop node kernel: MLP_A + residual + (optional) Z-emission ----------------
// x2 and the h tile alias the x staging buffer (layer1 split compute/store with a
// barrier) -> LDS 42 -> 25.1 KB, 4 blocks/CU. Also zeroes accp/accc after reading
// (fuses the inter-hop memset; zeroAcc=0 on the last hop).

__global__ __launch_bounds__(256, 4) void node_a_kernel(
    const float* __restrict__ h, float* __restrict__ accp, float* __restrict__ accc,
    const float* __restrict__ invp, const float* __restrict__ invc,
    const float* __restrict__ pmask, const float* __restrict__ cmask,
    const float* __restrict__ stok, const float* __restrict__ etok,
    const bf16* __restrict__ W1t, const float* __restrict__ B1,
    const bf16* __restrict__ W2t, const float* __restrict__ B2,
    const bf16* __restrict__ Pw1t, const bf16* __restrict__ Cw1t,
    bf16* __restrict__ Zbuf, int emitZ, int zeroAcc,
    float* __restrict__ hout, int N) {
  __shared__ __attribute__((aligned(16))) char ubuf[NB * AS * 2];  // 25088 B
  bf16* x = (bf16*)ubuf;   // staged [h | s_p | s_c], stride AS
  bf16* x2 = (bf16*)ubuf;  // after layer1, stride XS (16896 B)
  bf16* xh = (bf16*)ubuf;  // h tile for emit_z, stride TS (8704 B)
  const int t = threadIdx.x;
  const int r0 = blockIdx.x * NB;
  {
    const int r = t >> 3, c0 = (t & 7) * 16;
    int g = r0 + r; if (g >= N) g = N - 1;
    stage16(h + (size_t)g * D_DIM + c0, &x[r * AS + c0]);
  }
  {
    const int j = t;  // cols 128..383
    for (int r = 0; r < NB; ++r) {
      int g = r0 + r; if (g >= N) g = N - 1;
      float v;
      if (j < 128) {
        float* pa = &accp[(size_t)g * D_DIM + j];
        v = *pa * invp[g] + pmask[g] * stok[j];
        if (zeroAcc) *pa = 0.f;  // fused inter-hop memset (each (g,j) owned by one thread)
      } else {
        int jj = j - 128;
        float* pa = &accc[(size_t)g * D_DIM + jj];
        v = *pa * invc[g] + cmask[g] * etok[jj];
        if (zeroAcc) *pa = 0.f;
      }
      x[r * AS + 128 + j] = (bf16)v;
    }
  }
  __syncthreads();
  const int lane = t & 63, w = t >> 6, col = lane & 15, quad = lane >> 4;
  f32x4 acc1[2][4] = {};
  mlp_layer1_compute<3>(x, x + 128, x + 256, AS, W1t, acc1, lane, w);
  __syncthreads();  // all x reads done; x2 may overwrite
  mlp_layer1_store(acc1, B1, x2, lane, w);
  __syncthreads();
  f32x4 acc2[2][2] = {};
  mlp_layer2(x2, W2t, lane, w, acc2);
  __syncthreads();  // x2 reads done; xh may overwrite
#pragma unroll
  for (int nt = 0; nt < 2; ++nt) {
    const int n = w * 32 + nt * 16 + col;
    const float b2 = B2[n];
#pragma unroll
    for (int mt = 0; mt < 2; ++mt)
#pragma unroll
      for (int i = 0; i < 4; ++i) {
        int m = mt * 16 + quad * 4 + i;
        int g = r0 + m;
        int gc = g < N ? g : N - 1;
        float mlpv = acc2[mt][nt][i] + b2;
        mlpv = mlpv > 0.f ? mlpv : 0.f;
        float v = h[(size_t)gc * D_DIM + n] + mlpv;  // exact f32 residual
        v = v > 0.f ? v : 0.f;
        xh[m * TS + n] = (bf16)v;  // h tile for Z emission
        if (g < N) hout[(size_t)g * D_DIM + n] = v;
      }
  }
  if (emitZ) {
    __syncthreads();  // h tile ready
    emit_z(xh, TS, Pw1t, Cw1t, Zbuf, r0, N, lane, w);
  }
}

// ---------------- host launch ----------------

extern "C" void kernel_launch(void* const* d_in, const int* in_sizes, int n_in,
                              void* d_out, int out_size, void* d_ws, size_t ws_size,
                              hipStream_t stream) {
  const float* batch_token = (const float*)d_in[0];
  const int* epn = (const int*)d_in[1];
  const int* ecn = (const int*)d_in[2];
  const float* epi = (const float*)d_in[3];
  const float* eci = (const float*)d_in[4];
  const float* pmask = (const float*)d_in[5];
  const float* cmask = (const float*)d_in[6];
  const float* stok = (const float*)d_in[7];
  const float* etok = (const float*)d_in[8];
  const float *Vw1 = (const float*)d_in[9], *Vb1 = (const float*)d_in[10],
              *Vw2 = (const float*)d_in[11], *Vb2 = (const float*)d_in[12];
  const float *Ew1 = (const float*)d_in[13], *Eb1 = (const float*)d_in[14],
              *Ew2 = (const float*)d_in[15], *Eb2 = (const float*)d_in[16];
  const float *Pw1 = (const float*)d_in[17], *Pb1 = (const float*)d_in[18],
              *Pw2 = (const float*)d_in[19], *Pb2 = (const float*)d_in[20];
  const float *Cw1 = (const float*)d_in[21], *Cb1 = (const float*)d_in[22],
              *Cw2 = (const float*)d_in[23], *Cb2 = (const float*)d_in[24];
  const float *Aw1 = (const float*)d_in[25], *Ab1 = (const float*)d_in[26],
              *Aw2 = (const float*)d_in[27], *Ab2 = (const float*)d_in[28];
  const int N = in_sizes[5];  // p_mask length
  const int E = in_sizes[1];  // edge_p_node length

  char* ws = (char*)d_ws;
  size_t off = 0;
  auto alloc = [&](size_t bytes) {
    size_t o = off;
    off += (bytes + 511) & ~(size_t)511;
    return o;
  };
  float* accp = (float*)(ws + alloc((size_t)N * D_DIM * 4));
  float* accc = (float*)(ws + alloc((size_t)N * D_DIM * 4));
  bf16* Zbuf = (bf16*)(ws + alloc((size_t)4 * N * 256 * 2));  // ZO_P, ZW_P, ZO_C, ZW_C
  float* invp = (float*)(ws + alloc((size_t)N * 4));
  float* invc = (float*)(ws + alloc((size_t)N * 4));
  int* cntp = (int*)(ws + alloc((size_t)N * 4));
  int* cntc = (int*)(ws + alloc((size_t)N * 4));
  int* offp = (int*)(ws + alloc((size_t)N * 4));
  int* offc = (int*)(ws + alloc((size_t)N * 4));
  int* curp = (int*)(ws + alloc((size_t)N * 4));
  int* curc = (int*)(ws + alloc((size_t)N * 4));
  int* ownp_s = (int*)(ws + alloc((size_t)E * 4));
  int* othp_s = (int*)(ws + alloc((size_t)E * 4));
  float* xp_s = (float*)(ws + alloc((size_t)E * 4));
  int* ownc_s = (int*)(ws + alloc((size_t)E * 4));
  int* othc_s = (int*)(ws + alloc((size_t)E * 4));
  float* xc_s = (float*)(ws + alloc((size_t)E * 4));
  bf16* Vw1t = (bf16*)(ws + alloc(128 * 256 * 2));
  bf16* Pw1t = (bf16*)(ws + alloc(384 * 256 * 2));
  bf16* Cw1t = (bf16*)(ws + alloc(384 * 256 * 2));
  bf16* Aw1t = (bf16*)(ws + alloc(384 * 256 * 2));
  bf16* Vw2t = (bf16*)(ws + alloc(256 * 128 * 2));
  bf16* Pw2t = (bf16*)(ws + alloc(256 * 128 * 2));
  bf16* Cw2t = (bf16*)(ws + alloc(256 * 128 * 2));
  bf16* Aw2t = (bf16*)(ws + alloc(256 * 128 * 2));
  float* ets  = (float*)(ws + alloc(256 * 4));
  float* Atab = (float*)(ws + alloc((size_t)257 * 128 * 4));
  float* Btab = (float*)(ws + alloc((size_t)257 * 128 * 4));
  float* hbuf = (float*)d_out;  // h f32 lives in d_out across hops
  (void)ws_size; (void)n_in; (void)out_size;

  const dim3 blk(256);
  // weight transposes (f32 -> bf16): out[n*K+k] = in[k*N+n]
  transpose_kernel<<<dim3(1, 256), blk, 0, stream>>>(Vw1, Vw1t, 128, 256);
  transpose_kernel<<<dim3(2, 256), blk, 0, stream>>>(Pw1, Pw1t, 384, 256);
  transpose_kernel<<<dim3(2, 256), blk, 0, stream>>>(Cw1, Cw1t, 384, 256);
  transpose_kernel<<<dim3(2, 256), blk, 0, stream>>>(Aw1, Aw1t, 384, 256);
  transpose_kernel<<<dim3(1, 128), blk, 0, stream>>>(Vw2, Vw2t, 256, 128);
  transpose_kernel<<<dim3(1, 128), blk, 0, stream>>>(Pw2, Pw2t, 256, 128);
  transpose_kernel<<<dim3(1, 128), blk, 0, stream>>>(Cw2, Cw2t, 256, 128);
  transpose_kernel<<<dim3(1, 128), blk, 0, stream>>>(Aw2, Aw2t, 256, 128);

  // one-time E-MLP piecewise-affine tables (parallel: 128 column-blocks)
  emlp_table_kernel<<<dim3(128), dim3(256), 0, stream>>>(Ew1, Eb1, Ew2, Eb2, ets, Atab, Btab);

  // degree counts -> reciprocals; counting sort emitting sorted (own,oth,x) per side
  const size_t cntbytes = (size_t)((char*)(cntc + N) - (char*)cntp);
  hipMemsetAsync(cntp, 0, cntbytes, stream);
  count_kernel<<<dim3((E + 255) / 256), blk, 0, stream>>>(epn, ecn, cntp, cntc, E, N);
  inv_kernel<<<dim3((N + 255) / 256), blk, 0, stream>>>(cntp, cntc, invp, invc, N);
  scan_pair_kernel<<<dim3(2), dim3(1024), 0, stream>>>(cntp, cntc, offp, offc, N);
  const size_t curbytes = (size_t)((char*)(curc + N) - (char*)curp);
  hipMemsetAsync(curp, 0, curbytes, stream);
  scatter_kernel<<<dim3((E + 255) / 256), blk, 0, stream>>>(
      epn, ecn, epi, eci, offp, offc, curp, curc,
      ownp_s, othp_s, xp_s, ownc_s, othc_s, xc_s, E, N);

  const int nblocks = (N + NB - 1) / NB;
  const int eblocks = (E + EB - 1) / EB;

  // h = MLP_V(batch_token) (f32 into d_out) + Z for hop 0
  node_v_kernel<<<dim3(nblocks), blk, 0, stream>>>(
      batch_token, Vw1t, Vb1, Vw2t, Vb2, Pw1t, Cw1t, Zbuf, hbuf, N);

  const size_t accbytes = (size_t)((char*)(accc + (size_t)N * D_DIM) - (char*)accp);
  hipMemsetAsync(accp, 0, accbytes, stream);  // hop 0 only; node_a zeroes for later hops
  for (int hop = 0; hop < 3; ++hop) {
    edge_side_kernel<<<dim3(eblocks, 2), dim3(1024), 0, stream>>>(
        Zbuf, ownp_s, othp_s, xp_s, ownc_s, othc_s, xc_s, ets, Atab, Btab,
        Pw1t, Pb1, Pw2t, Pb2, Cw1t, Cb1, Cw2t, Cb2, accp, accc, E, N);
    node_a_kernel<<<dim3(nblocks), blk, 0, stream>>>(
        hbuf, accp, accc, invp, invc, pmask, cmask, stok, etok,
        Aw1t, Ab1, Aw2t, Ab2, Pw1t, Cw1t, Zbuf, (hop < 2) ? 1 : 0, (hop < 2) ? 1 : 0,
        hbuf, N);
  }
}

// Round 15
// 1954.191 us; speedup vs baseline: 1.0548x; 1.0548x over previous
//
#include <hip/hip_runtime.h>
#include <hip/hip_bf16.h>
#include <cstdint>
#include <cstddef>
#include <cmath>

typedef __bf16 bf16;
typedef bf16 bf16x8 __attribute__((ext_vector_type(8)));
typedef float f32x4 __attribute__((ext_vector_type(4)));

#define D_DIM 128
#define NB 32      // nodes per tile (node kernels)
#define EB 128     // edges per tile (edge kernel)
#define TS 136     // LDS stride for 128-wide bf16 tiles (+8 pad)
#define XS 264     // LDS stride for 256-wide bf16 tile (+8 pad)
#define SRS 132    // LDS stride for 128-wide f32 sred tile
#define AS 392     // LDS stride for 384-wide node-A input tile

__device__ __forceinline__ f32x4 mfma16(bf16x8 a, bf16x8 b, f32x4 c) {
  return __builtin_amdgcn_mfma_f32_16x16x32_bf16(a, b, c, 0, 0, 0);
}

__device__ __forceinline__ int clampi(int v, int hi) {
  return v < 0 ? 0 : (v > hi ? hi : v);
}

// stage 16 consecutive f32 (64B, aligned) -> 16 bf16 in LDS
__device__ __forceinline__ void stage16(const float* __restrict__ src, bf16* dst) {
  bf16 tmp[16];
#pragma unroll
  for (int q = 0; q < 4; ++q) {
    f32x4 f = ((const f32x4*)src)[q];
#pragma unroll
    for (int j = 0; j < 4; ++j) tmp[q * 4 + j] = (bf16)f[j];
  }
  *(bf16x8*)dst = *(bf16x8*)tmp;
  *(bf16x8*)(dst + 8) = *(bf16x8*)(tmp + 8);
}

// ---- layer1 (node kernels): A[32 x K] from LDS segments @ W1t[256 x K]^T -> x2
template <int NSEG>
__device__ __forceinline__ void mlp_layer1(const bf16* s0, const bf16* s1, const bf16* s2,
                                           const int S,
                                           const bf16* __restrict__ W1t,
                                           const float* __restrict__ B1,
                                           bf16* x2, const int lane, const int w) {
  const int col = lane & 15, quad = lane >> 4;
  const int K = NSEG * 128;
  f32x4 acc[2][4] = {};
  const bf16* segs[3] = {s0, s1, s2};
#pragma unroll
  for (int sg = 0; sg < NSEG; ++sg) {
    const bf16* xl = segs[sg];
#pragma unroll
    for (int kk = 0; kk < 128; kk += 32) {
      const int k0 = sg * 128 + kk;
      bf16x8 a0 = *(const bf16x8*)&xl[col * S + kk + quad * 8];
      bf16x8 a1 = *(const bf16x8*)&xl[(col + 16) * S + kk + quad * 8];
#pragma unroll
      for (int nt = 0; nt < 4; ++nt) {
        bf16x8 b = *(const bf16x8*)(W1t + (size_t)(w * 64 + nt * 16 + col) * K + k0 + quad * 8);
        acc[0][nt] = mfma16(a0, b, acc[0][nt]);
        acc[1][nt] = mfma16(a1, b, acc[1][nt]);
      }
    }
  }
#pragma unroll
  for (int nt = 0; nt < 4; ++nt) {
    const int n = w * 64 + nt * 16 + col;
    const float b1 = B1[n];
#pragma unroll
    for (int mt = 0; mt < 2; ++mt)
#pragma unroll
      for (int i = 0; i < 4; ++i) {
        float v = acc[mt][nt][i] + b1;
        x2[(mt * 16 + quad * 4 + i) * XS + n] = (bf16)(v > 0.f ? v : 0.f);
      }
  }
}

// ---- layer2: x2[32 x 256] @ W2t[128 x 256]^T -> acc2
__device__ __forceinline__ void mlp_layer2(const bf16* x2, const bf16* __restrict__ W2t,
                                           const int lane, const int w, f32x4 acc2[2][2]) {
  const int col = lane & 15, quad = lane >> 4;
#pragma unroll
  for (int k0 = 0; k0 < 256; k0 += 32) {
    bf16x8 a0 = *(const bf16x8*)&x2[col * XS + k0 + quad * 8];
    bf16x8 a1 = *(const bf16x8*)&x2[(col + 16) * XS + k0 + quad * 8];
#pragma unroll
    for (int nt = 0; nt < 2; ++nt) {
      bf16x8 b = *(const bf16x8*)(W2t + (size_t)(w * 32 + nt * 16 + col) * 256 + k0 + quad * 8);
      acc2[0][nt] = mfma16(a0, b, acc2[0][nt]);
      acc2[1][nt] = mfma16(a1, b, acc2[1][nt]);
    }
  }
}

// ---- Z emission: Z[w] = x(bf16 h tile, stride S) @ W1-slice, w in {P-oth,P-own,C-oth,C-own}
__device__ __forceinline__ void emit_z(const bf16* x, const int S,
                                       const bf16* __restrict__ Pw1t,
                                       const bf16* __restrict__ Cw1t,
                                       bf16* __restrict__ Zbuf,
                                       const int r0, const int N,
                                       const int lane, const int w) {
  const int col = lane & 15, quad = lane >> 4;
  const bf16* base = ((w & 2) ? Cw1t : Pw1t) + (w & 1) * 128;  // k-offset slice, row-stride 384
  bf16* out = Zbuf + (size_t)w * ((size_t)N * 256);
#pragma unroll
  for (int half = 0; half < 2; ++half) {
    f32x4 acc[2][8] = {};
#pragma unroll
    for (int kc = 0; kc < 4; ++kc) {
      bf16x8 a0 = *(const bf16x8*)&x[col * S + kc * 32 + quad * 8];
      bf16x8 a1 = *(const bf16x8*)&x[(col + 16) * S + kc * 32 + quad * 8];
#pragma unroll
      for (int nt = 0; nt < 8; ++nt) {
        const int n = half * 128 + nt * 16 + col;
        bf16x8 b = *(const bf16x8*)(base + (size_t)n * 384 + kc * 32 + quad * 8);
        acc[0][nt] = mfma16(a0, b, acc[0][nt]);
        acc[1][nt] = mfma16(a1, b, acc[1][nt]);
      }
    }
#pragma unroll
    for (int nt = 0; nt < 8; ++nt) {
      const int n = half * 128 + nt * 16 + col;
#pragma unroll
      for (int mt = 0; mt < 2; ++mt)
#pragma unroll
        for (int i = 0; i < 4; ++i) {
          int g = r0 + mt * 16 + quad * 4 + i;
          if (g < N) out[(size_t)g * 256 + n] = (bf16)acc[mt][nt][i];
        }
    }
  }
}

// ---------------- small utility kernels ----------------

// f32 [K,N] -> bf16 [N,K]
__global__ void transpose_kernel(const float* __restrict__ in, bf16* __restrict__ out,
                                 int K, int N) {
  int k = blockIdx.x * blockDim.x + threadIdx.x;
  int n = blockIdx.y;
  if (k < K) out[(size_t)n * K + k] = (bf16)in[(size_t)k * N + n];
}

__global__ void count_kernel(const int* __restrict__ epn, const int* __restrict__ ecn,
                             int* cntp, int* cntc, int E, int N) {
  int i = blockIdx.x * blockDim.x + threadIdx.x;
  if (i < E) {
    atomicAdd(&cntp[clampi(epn[i], N - 1)], 1);
    atomicAdd(&cntc[clampi(ecn[i], N - 1)], 1);
  }
}

__global__ void inv_kernel(const int* __restrict__ cntp, const int* __restrict__ cntc,
                           float* invp, float* invc, int N) {
  int i = blockIdx.x * blockDim.x + threadIdx.x;
  if (i < N) {
    invp[i] = 1.f / fmaxf((float)cntp[i], 1.f);
    invc[i] = 1.f / fmaxf((float)cntc[i], 1.f);
  }
}

// exclusive scan; blockIdx.x selects (cntp->offp) or (cntc->offc), both run in parallel
__global__ void scan_pair_kernel(const int* __restrict__ cntp, const int* __restrict__ cntc,
                                 int* __restrict__ offp, int* __restrict__ offc, int n) {
  const int* cnt = blockIdx.x ? cntc : cntp;
  int* offs = blockIdx.x ? offc : offp;
  __shared__ int buf[1024];
  __shared__ int carry;
  const int t = threadIdx.x;
  if (t == 0) carry = 0;
  __syncthreads();
  for (int base = 0; base < n; base += 1024) {
    int v = (base + t < n) ? cnt[base + t] : 0;
    buf[t] = v;
    __syncthreads();
    for (int d = 1; d < 1024; d <<= 1) {
      int add = (t >= d) ? buf[t - d] : 0;
      __syncthreads();
      buf[t] += add;
      __syncthreads();
    }
    if (base + t < n) offs[base + t] = carry + buf[t] - v;  // exclusive
    __syncthreads();
    if (t == 1023) carry += buf[1023];
    __syncthreads();
  }
}

// counting-sort scatter: emit per-side (own, oth, x) directly in SORTED edge order,
// removing the 2-deep index-gather chain from every edge-kernel tile. [r14 verified:
// edge FETCH 405 -> 253 MB, dur 420 -> 410]
__global__ void scatter_kernel(const int* __restrict__ epn, const int* __restrict__ ecn,
                               const float* __restrict__ epi, const float* __restrict__ eci,
                               const int* __restrict__ offp, const int* __restrict__ offc,
                               int* curp, int* curc,
                               int* ownp_s, int* othp_s, float* xp_s,
                               int* ownc_s, int* othc_s, float* xc_s, int E, int N) {
  int i = blockIdx.x * blockDim.x + threadIdx.x;
  if (i < E) {
    int p = clampi(epn[i], N - 1);
    int c = clampi(ecn[i], N - 1);
    int pp = offp[p] + atomicAdd(&curp[p], 1);
    ownp_s[pp] = p; othp_s[pp] = c; xp_s[pp] = epi[i];
    int pc = offc[c] + atomicAdd(&curc[c], 1);
    ownc_s[pc] = c; othc_s[pc] = p; xc_s[pc] = eci[i];
  }
}

// ---------------- one-time E-MLP collapse: piecewise-affine tables (parallel) ----------------
// feat(x) = relu(Ew2^T relu(x*Ew1+Eb1) + Eb2) is piecewise-linear in scalar x with
// breakpoints t_k = -Eb1[k]/Ew1[k]. Within segment s: feat_pre = x*Atab[s] + Btab[s].
// Grid: 128 blocks (one output column each) x 256 threads (one hidden unit each).

__global__ __launch_bounds__(256) void emlp_table_kernel(
    const float* __restrict__ Ew1, const float* __restrict__ Eb1,
    const float* __restrict__ Ew2, const float* __restrict__ Eb2,
    float* __restrict__ ts_out, float* __restrict__ Atab, float* __restrict__ Btab) {
  __shared__ float s_tk[256], s_w[256], s_b[256];
  __shared__ int s_k[256];
  __shared__ float sA[256], sB[256];
  const int j = blockIdx.x;  // column 0..127
  const int t = threadIdx.x;
  float w = Ew1[t], b = Eb1[t];
  float tk = (w != 0.f) ? (-b / w) : INFINITY;  // w==0: never toggles
  s_tk[t] = tk; s_w[t] = w; s_b[t] = b;
  __syncthreads();
  // rank sort (ties broken by index)
  int rank = 0;
  for (int u = 0; u < 256; ++u) {
    float tu = s_tk[u];
    if (tu < tk || (tu == tk && u < t)) ++rank;
  }
  s_k[rank] = t;
  if (j == 0) ts_out[rank] = tk;
  // base segment (x -> -inf): unit active iff w<0, or w==0 && b>0
  float w2own = Ew2[(size_t)t * 128 + j];
  bool act = (w < 0.f || (w == 0.f && b > 0.f));
  sA[t] = act ? w * w2own : 0.f;
  sB[t] = act ? b * w2own : 0.f;
  __syncthreads();
  for (int d = 128; d > 0; d >>= 1) {
    if (t < d) { sA[t] += sA[t + d]; sB[t] += sB[t + d]; }
    __syncthreads();
  }
  const float baseA = sA[0], baseB = sB[0];
  __syncthreads();
  // per-sorted-position delta (crossing upward: w>0 activates, w<0 deactivates)
  int k = s_k[t];
  float wk = s_w[k], bk = s_b[k];
  float dA = 0.f, dB = 0.f;
  if (wk != 0.f) {
    float w2 = Ew2[(size_t)k * 128 + j];
    float sgn = wk > 0.f ? 1.f : -1.f;
    dA = sgn * wk * w2;
    dB = sgn * bk * w2;
  }
  sA[t] = dA; sB[t] = dB;
  __syncthreads();
  // inclusive Hillis-Steele scan
  for (int d = 1; d < 256; d <<= 1) {
    float aA = (t >= d) ? sA[t - d] : 0.f;
    float aB = (t >= d) ? sB[t - d] : 0.f;
    __syncthreads();
    sA[t] += aA; sB[t] += aB;
    __syncthreads();
  }
  const float eb2 = Eb2[j];
  if (t == 0) { Atab[j] = baseA; Btab[j] = baseB + eb2; }
  Atab[(size_t)(t + 1) * 128 + j] = baseA + sA[t];
  Btab[(size_t)(t + 1) * 128 + j] = baseB + sB[t] + eb2;
}

// ---------------- MLP_V + Z-emission: h = mlp(batch_token); Z = h @ W1-slices ----------------

__global__ __launch_bounds__(256, 3) void node_v_kernel(
    const float* __restrict__ bt, const bf16* __restrict__ W1t, const float* __restrict__ B1,
    const bf16* __restrict__ W2t, const float* __restrict__ B2,
    const bf16* __restrict__ Pw1t, const bf16* __restrict__ Cw1t,
    bf16* __restrict__ Zbuf, float* __restrict__ hout, int N) {
  __shared__ __attribute__((aligned(16))) bf16 x[NB * TS];
  __shared__ __attribute__((aligned(16))) bf16 x2[NB * XS];
  const int t = threadIdx.x;
  const int r0 = blockIdx.x * NB;
  {
    const int r = t >> 3, c0 = (t & 7) * 16;
    int g = r0 + r; if (g >= N) g = N - 1;
    stage16(bt + (size_t)g * D_DIM + c0, &x[r * TS + c0]);
  }
  __syncthreads();
  const int lane = t & 63, w = t >> 6, col = lane & 15, quad = lane >> 4;
  mlp_layer1<1>(x, x, x, TS, W1t, B1, x2, lane, w);
  __syncthreads();
  f32x4 acc2[2][2] = {};
  mlp_layer2(x2, W2t, lane, w, acc2);
  __syncthreads();  // x reads (layer1) long done; safe to overwrite below
#pragma unroll
  for (int nt = 0; nt < 2; ++nt) {
    const int n = w * 32 + nt * 16 + col;
    const float b2 = B2[n];
#pragma unroll
    for (int mt = 0; mt < 2; ++mt)
#pragma unroll
      for (int i = 0; i < 4; ++i) {
        int m = mt * 16 + quad * 4 + i;
        int g = r0 + m;
        float v = acc2[mt][nt][i] + b2;
        v = v > 0.f ? v : 0.f;
        x[m * TS + n] = (bf16)v;  // h tile for Z emission
        if (g < N) hout[(size_t)g * D_DIM + n] = v;
      }
  }
  __syncthreads();  // h tile ready
  emit_z(x, TS, Pw1t, Cw1t, Zbuf, r0, N, lane, w);
}

// ---------------- per-hop edge kernel: EB=128, 1024 threads (16 waves), 2 blocks/CU ----
// z(e) = relu(ZO[oth(e)] + ZW[own(e)] + feat(x_e)@W1c + b1) ; out = z @ W2 ; segsum by own.
// Edge metadata pre-sorted (own/oth/x arrays) -> 3 coalesced loads, no gather chain.

__global__ __launch_bounds__(1024, 8) void edge_side_kernel(
    const bf16* __restrict__ Zbuf,
    const int* __restrict__ ownp_s, const int* __restrict__ othp_s,
    const float* __restrict__ xp_s,
    const int* __restrict__ ownc_s, const int* __restrict__ othc_s,
    const float* __restrict__ xc_s,
    const float* __restrict__ ets, const float* __restrict__ Atab,
    const float* __restrict__ Btab,
    const bf16* __restrict__ Pw1t, const float* __restrict__ Pb1,
    const bf16* __restrict__ Pw2t, const float* __restrict__ Pb2,
    const bf16* __restrict__ Cw1t, const float* __restrict__ Cb1,
    const bf16* __restrict__ Cw2t, const float* __restrict__ Cb2,
    float* __restrict__ accp, float* __restrict__ accc, int E, int N) {
  const int side = blockIdx.y;  // wave-uniform
  const size_t NZ = (size_t)N * 256;
  const bf16* ZO     = Zbuf + (size_t)(side * 2 + 0) * NZ;
  const bf16* ZW     = Zbuf + (size_t)(side * 2 + 1) * NZ;
  const int* owns    = side ? ownc_s : ownp_s;
  const int* oths    = side ? othc_s : othp_s;
  const float* xs    = side ? xc_s : xp_s;
  const bf16* W1c    = (side ? Cw1t : Pw1t) + 256;  // ep-slice, row-stride 384
  const float* B1    = side ? Cb1 : Pb1;
  const bf16* W2t    = side ? Cw2t : Pw2t;
  const float* B2    = side ? Cb2 : Pb2;
  float* acc         = side ? accc : accp;

  __shared__ int s_own[EB], s_oth[EB];  // s_own doubles as segment key; -1 = pad
  __shared__ float s_x[EB];
  __shared__ float s_ts[256];  // sorted breakpoints
  // union buffer: [feat 128x136 bf16 | xzh 128x136 bf16] ; sred 128x132 f32 aliases both
  __shared__ __attribute__((aligned(16))) char ubuf[EB * TS * 2 * 2];  // 69632 B
  bf16* feat = (bf16*)ubuf;
  bf16* xzh  = (bf16*)(ubuf + EB * TS * 2);
  float* sred = (float*)ubuf;  // 128*132*4 = 67584 <= 69632

  const int t = threadIdx.x;
  const int e0 = blockIdx.x * EB;
  if (t < 256) s_ts[t] = ets[t];
  if (t < EB) {
    int e = e0 + t;
    if (e < E) {
      s_own[t] = owns[e];
      s_oth[t] = oths[e];
      s_x[t] = xs[e];
    } else {
      s_own[t] = -1; s_oth[t] = 0; s_x[t] = 0.f;
    }
  }
  __syncthreads();  // b0: indices + breakpoints ready

  const int lane = t & 63, w = t >> 6, col = lane & 15, quad = lane >> 4;
  const int zr = t >> 3, zc = (t & 7) * 16;  // 8 threads/row, 16 cols each (per half)

  // ---- issue ZO half-0 gather EARLY (row pointers kept for later phases)
  const bf16* zo_row;
  const bf16* zw_row;
  bf16x8 va[2];
  {
    int ro = s_oth[zr];
    int rw = s_own[zr]; if (rw < 0) rw = 0;
    zo_row = ZO + (size_t)ro * 256;
    zw_row = ZW + (size_t)rw * 256;
#pragma unroll
    for (int q = 0; q < 2; ++q) va[q] = *(const bf16x8*)(zo_row + zc + q * 8);
  }

  // ---- feat via segment-affine tables (8 threads/edge, 16 cols; hides gather latency)
  {
    const float xv = s_x[zr];
    int lo = 0, hi = 256;
#pragma unroll
    for (int it = 0; it < 8; ++it) {
      int mid = (lo + hi) >> 1;
      if (s_ts[mid] < xv) lo = mid + 1; else hi = mid;
    }
    const float* Ar = Atab + (size_t)lo * 128 + zc;
    const float* Br = Btab + (size_t)lo * 128 + zc;
#pragma unroll
    for (int q = 0; q < 2; ++q) {
      f32x4 a0 = *(const f32x4*)(Ar + q * 8);
      f32x4 a1 = *(const f32x4*)(Ar + q * 8 + 4);
      f32x4 b0 = *(const f32x4*)(Br + q * 8);
      f32x4 b1v = *(const f32x4*)(Br + q * 8 + 4);
      bf16 o[8];
#pragma unroll
      for (int j = 0; j < 4; ++j) {
        float v0 = fmaf(xv, a0[j], b0[j]);
        float v1 = fmaf(xv, a1[j], b1v[j]);
        o[j] = (bf16)(v0 > 0.f ? v0 : 0.f);
        o[4 + j] = (bf16)(v1 > 0.f ? v1 : 0.f);
      }
      *(bf16x8*)&feat[zr * TS + zc + q * 8] = *(bf16x8*)o;
    }
  }

  // ---- zsum half-0 (va landed; ZW rows sort-clustered, L2-hot)
  {
#pragma unroll
    for (int q = 0; q < 2; ++q) {
      bf16x8 b = *(const bf16x8*)(zw_row + zc + q * 8);
      bf16 o[8];
#pragma unroll
      for (int j = 0; j < 8; ++j) o[j] = (bf16)((float)va[q][j] + (float)b[j]);
      *(bf16x8*)&xzh[zr * TS + zc + q * 8] = *(bf16x8*)o;
    }
  }
  __syncthreads();  // b1: feat + xzh(h0 zsum) ready

  // ---- issue ZO half-1 gather (covered by W1c + layer2 of half 0)
#pragma unroll
  for (int q = 0; q < 2; ++q) va[q] = *(const bf16x8*)(zo_row + 128 + zc + q * 8);

  f32x4 acc2[4];
#pragma unroll
  for (int g = 0; g < 4; ++g) acc2[g] = (f32x4){0.f, 0.f, 0.f, 0.f};

  const int nh = (w & 7) * 16 + col;  // wave's column within the current 128-wide half
  const int rbase = (w >> 3) * 64;    // wave's row-half of the 128-edge tile

  // ---- half 0: W1c GEMM + fused z-add + relu (in place), then layer2 partial
  {
    f32x4 acc1[4] = {};
#pragma unroll
    for (int kc = 0; kc < 4; ++kc) {
      bf16x8 b = *(const bf16x8*)(W1c + (size_t)nh * 384 + kc * 32 + quad * 8);
#pragma unroll
      for (int g = 0; g < 4; ++g) {
        bf16x8 afr = *(const bf16x8*)&feat[(rbase + g * 16 + col) * TS + kc * 32 + quad * 8];
        acc1[g] = mfma16(afr, b, acc1[g]);
      }
    }
    const float b1v = B1[nh];
#pragma unroll
    for (int g = 0; g < 4; ++g)
#pragma unroll
      for (int i = 0; i < 4; ++i) {
        const int m = rbase + g * 16 + quad * 4 + i;
        float v = acc1[g][i] + b1v + (float)xzh[m * TS + nh];
        xzh[m * TS + nh] = (bf16)(v > 0.f ? v : 0.f);
      }
  }
  __syncthreads();  // b2: xzh = relu(z h0) ready
#pragma unroll
  for (int kc = 0; kc < 4; ++kc) {
    bf16x8 b = *(const bf16x8*)(W2t + (size_t)nh * 256 + kc * 32 + quad * 8);
#pragma unroll
    for (int g = 0; g < 4; ++g) {
      bf16x8 afr = *(const bf16x8*)&xzh[(rbase + g * 16 + col) * TS + kc * 32 + quad * 8];
      acc2[g] = mfma16(afr, b, acc2[g]);
    }
  }
  __syncthreads();  // b3: xzh(h0) reads done

  // ---- zsum half-1
  {
#pragma unroll
    for (int q = 0; q < 2; ++q) {
      bf16x8 b = *(const bf16x8*)(zw_row + 128 + zc + q * 8);
      bf16 o[8];
#pragma unroll
      for (int j = 0; j < 8; ++j) o[j] = (bf16)((float)va[q][j] + (float)b[j]);
      *(bf16x8*)&xzh[zr * TS + zc + q * 8] = *(bf16x8*)o;
    }
  }
  __syncthreads();  // b4: xzh(h1 zsum) ready

  // ---- half 1: W1c GEMM + fused z-add + relu, then layer2 partial (k offset 128)
  {
    f32x4 acc1[4] = {};
#pragma unroll
    for (int kc = 0; kc < 4; ++kc) {
      bf16x8 b = *(const bf16x8*)(W1c + (size_t)(128 + nh) * 384 + kc * 32 + quad * 8);
#pragma unroll
      for (int g = 0; g < 4; ++g) {
        bf16x8 afr = *(const bf16x8*)&feat[(rbase + g * 16 + col) * TS + kc * 32 + quad * 8];
        acc1[g] = mfma16(afr, b, acc1[g]);
      }
    }
    const float b1v = B1[128 + nh];
#pragma unroll
    for (int g = 0; g < 4; ++g)
#pragma unroll
      for (int i = 0; i < 4; ++i) {
        const int m = rbase + g * 16 + quad * 4 + i;
        float v = acc1[g][i] + b1v + (float)xzh[m * TS + nh];
        xzh[m * TS + nh] = (bf16)(v > 0.f ? v : 0.f);
      }
  }
  __syncthreads();  // b5: xzh = relu(z h1) ready
#pragma unroll
  for (int kc = 0; kc < 4; ++kc) {
    bf16x8 b = *(const bf16x8*)(W2t + (size_t)nh * 256 + 128 + kc * 32 + quad * 8);
#pragma unroll
    for (int g = 0; g < 4; ++g) {
      bf16x8 afr = *(const bf16x8*)&xzh[(rbase + g * 16 + col) * TS + kc * 32 + quad * 8];
      acc2[g] = mfma16(afr, b, acc2[g]);
    }
  }
  __syncthreads();  // b6: xzh + feat dead; sred may overwrite

  // ---- sred write (wave-private cols x row-half) + segmented reduce + atomics
  {
    const float b2 = B2[nh];
#pragma unroll
    for (int g = 0; g < 4; ++g)
#pragma unroll
      for (int i = 0; i < 4; ++i) {
        float v = acc2[g][i] + b2;
        sred[(rbase + g * 16 + quad * 4 + i) * SRS + nh] = v > 0.f ? v : 0.f;
      }
  }
  __syncthreads();  // b7: sred fully written
  {
    const int c = t & 127;          // column
    const int rlo = (t >> 7) * 16;  // 8 segments of 16 rows
    float run = 0.f;
    int cur = s_own[rlo];
    for (int r = rlo; r < rlo + 16; ++r) {
      int k = s_own[r];
      if (k != cur) {
        if (cur >= 0)
          __hip_atomic_fetch_add(&acc[(size_t)cur * D_DIM + c], run,
                                 __ATOMIC_RELAXED, __HIP_MEMORY_SCOPE_AGENT);
        run = 0.f;
        cur = k;
      }
      run += sred[r * SRS + c];
    }
    if (cur >= 0)
      __hip_atomic_fetch_add(&acc[(size_t)cur * D_DIM + c], run,
                             __ATOMIC_RELAXED, __HIP_MEMORY_SCOPE_AGENT);
  }
}

// ---------------- per-hop node kernel: MLP_A + residual + (optional) Z-emission ----------------

__global__ __launch_bounds__(256, 3) void node_a_kernel(
    const float* __restrict__ h, const float* __restrict__ accp, const float* __restrict__ accc,
    const float* __restrict__ invp, const float* __restrict__ invc,
    const float* __restrict__ pmask, const float* __restrict__ cmask,
    const float* __restrict__ stok, const float* __restrict__ etok,
    const bf16* __restrict__ W1t, const float* __restrict__ B1,
    const bf16* __restrict__ W2t, const float* __restrict__ B2,
    const bf16* __restrict__ Pw1t, const bf16* __restrict__ Cw1t,
    bf16* __restrict__ Zbuf, int emitZ,
    float* __restrict__ hout, int N) {
  __shared__ __attribute__((aligned(16))) bf16 x[NB * AS];  // [h | s_p | s_c]
  __shared__ __attribute__((aligned(16))) bf16 x2[NB * XS];
  const int t = threadIdx.x;
  const int r0 = blockIdx.x * NB;
  {
    const int r = t >> 3, c0 = (t & 7) * 16;
    int g = r0 + r; if (g >= N) g = N - 1;
    stage16(h + (size_t)g * D_DIM + c0, &x[r * AS + c0]);
  }
  {
    const int j = t;  // cols 128..383
    for (int r = 0; r < NB; ++r) {
      int g = r0 + r; if (g >= N) g = N - 1;
      float v;
      if (j < 128)
        v = accp[(size_t)g * D_DIM + j] * invp[g] + pmask[g] * stok[j];
      else {
        int jj = j - 128;
        v = accc[(size_t)g * D_DIM + jj] * invc[g] + cmask[g] * etok[jj];
      }
      x[r * AS + 128 + j] = (bf16)v;
    }
  }
  __syncthreads();
  const int lane = t & 63, w = t >> 6, col = lane & 15, quad = lane >> 4;
  mlp_layer1<3>(x, x + 128, x + 256, AS, W1t, B1, x2, lane, w);
  __syncthreads();
  f32x4 acc2[2][2] = {};
  mlp_layer2(x2, W2t, lane, w, acc2);
  __syncthreads();  // x reads (layer1) long done; safe to overwrite below
#pragma unroll
  for (int nt = 0; nt < 2; ++nt) {
    const int n = w * 32 + nt * 16 + col;
    const float b2 = B2[n];
#pragma unroll
    for (int mt = 0; mt < 2; ++mt)
#pragma unroll
      for (int i = 0; i < 4; ++i) {
        int m = mt * 16 + quad * 4 + i;
        int g = r0 + m;
        int gc = g < N ? g : N - 1;
        float mlpv = acc2[mt][nt][i] + b2;
        mlpv = mlpv > 0.f ? mlpv : 0.f;
        float v = h[(size_t)gc * D_DIM + n] + mlpv;  // exact f32 residual
        v = v > 0.f ? v : 0.f;
        x[m * AS + n] = (bf16)v;  // h tile for Z emission
        if (g < N) hout[(size_t)g * D_DIM + n] = v;
      }
  }
  if (emitZ) {
    __syncthreads();  // h tile ready
    emit_z(x, AS, Pw1t, Cw1t, Zbuf, r0, N, lane, w);
  }
}

// ---------------- host launch ----------------

extern "C" void kernel_launch(void* const* d_in, const int* in_sizes, int n_in,
                              void* d_out, int out_size, void* d_ws, size_t ws_size,
                              hipStream_t stream) {
  const float* batch_token = (const float*)d_in[0];
  const int* epn = (const int*)d_in[1];
  const int* ecn = (const int*)d_in[2];
  const float* epi = (const float*)d_in[3];
  const float* eci = (const float*)d_in[4];
  const float* pmask = (const float*)d_in[5];
  const float* cmask = (const float*)d_in[6];
  const float* stok = (const float*)d_in[7];
  const float* etok = (const float*)d_in[8];
  const float *Vw1 = (const float*)d_in[9], *Vb1 = (const float*)d_in[10],
              *Vw2 = (const float*)d_in[11], *Vb2 = (const float*)d_in[12];
  const float *Ew1 = (const float*)d_in[13], *Eb1 = (const float*)d_in[14],
              *Ew2 = (const float*)d_in[15], *Eb2 = (const float*)d_in[16];
  const float *Pw1 = (const float*)d_in[17], *Pb1 = (const float*)d_in[18],
              *Pw2 = (const float*)d_in[19], *Pb2 = (const float*)d_in[20];
  const float *Cw1 = (const float*)d_in[21], *Cb1 = (const float*)d_in[22],
              *Cw2 = (const float*)d_in[23], *Cb2 = (const float*)d_in[24];
  const float *Aw1 = (const float*)d_in[25], *Ab1 = (const float*)d_in[26],
              *Aw2 = (const float*)d_in[27], *Ab2 = (const float*)d_in[28];
  const int N = in_sizes[5];  // p_mask length
  const int E = in_sizes[1];  // edge_p_node length

  char* ws = (char*)d_ws;
  size_t off = 0;
  auto alloc = [&](size_t bytes) {
    size_t o = off;
    off += (bytes + 511) & ~(size_t)511;
    return o;
  };
  float* accp = (float*)(ws + alloc((size_t)N * D_DIM * 4));
  float* accc = (float*)(ws + alloc((size_t)N * D_DIM * 4));
  bf16* Zbuf = (bf16*)(ws + alloc((size_t)4 * N * 256 * 2));  // ZO_P, ZW_P, ZO_C, ZW_C
  float* invp = (float*)(ws + alloc((size_t)N * 4));
  float* invc = (float*)(ws + alloc((size_t)N * 4));
  int* cntp = (int*)(ws + alloc((size_t)N * 4));
  int* cntc = (int*)(ws + alloc((size_t)N * 4));
  int* offp = (int*)(ws + alloc((size_t)N * 4));
  int* offc = (int*)(ws + alloc((size_t)N * 4));
  int* curp = (int*)(ws + alloc((size_t)N * 4));
  int* curc = (int*)(ws + alloc((size_t)N * 4));
  int* ownp_s = (int*)(ws + alloc((size_t)E * 4));
  int* othp_s = (int*)(ws + alloc((size_t)E * 4));
  float* xp_s = (float*)(ws + alloc((size_t)E * 4));
  int* ownc_s = (int*)(ws + alloc((size_t)E * 4));
  int* othc_s = (int*)(ws + alloc((size_t)E * 4));
  float* xc_s = (float*)(ws + alloc((size_t)E * 4));
  bf16* Vw1t = (bf16*)(ws + alloc(128 * 256 * 2));
  bf16* Pw1t = (bf16*)(ws + alloc(384 * 256 * 2));
  bf16* Cw1t = (bf16*)(ws + alloc(384 * 256 * 2));
  bf16* Aw1t = (bf16*)(ws + alloc(384 * 256 * 2));
  bf16* Vw2t = (bf16*)(ws + alloc(256 * 128 * 2));
  bf16* Pw2t = (bf16*)(ws + alloc(256 * 128 * 2));
  bf16* Cw2t = (bf16*)(ws + alloc(256 * 128 * 2));
  bf16* Aw2t = (bf16*)(ws + alloc(256 * 128 * 2));
  float* ets  = (float*)(ws + alloc(256 * 4));
  float* Atab = (float*)(ws + alloc((size_t)257 * 128 * 4));
  float* Btab = (float*)(ws + alloc((size_t)257 * 128 * 4));
  float* hbuf = (float*)d_out;  // h f32 lives in d_out across hops
  (void)ws_size; (void)n_in; (void)out_size;

  const dim3 blk(256);
  // weight transposes (f32 -> bf16): out[n*K+k] = in[k*N+n]
  transpose_kernel<<<dim3(1, 256), blk, 0, stream>>>(Vw1, Vw1t, 128, 256);
  transpose_kernel<<<dim3(2, 256), blk, 0, stream>>>(Pw1, Pw1t, 384, 256);
  transpose_kernel<<<dim3(2, 256), blk, 0, stream>>>(Cw1, Cw1t, 384, 256);
  transpose_kernel<<<dim3(2, 256), blk, 0, stream>>>(Aw1, Aw1t, 384, 256);
  transpose_kernel<<<dim3(1, 128), blk, 0, stream>>>(Vw2, Vw2t, 256, 128);
  transpose_kernel<<<dim3(1, 128), blk, 0, stream>>>(Pw2, Pw2t, 256, 128);
  transpose_kernel<<<dim3(1, 128), blk, 0, stream>>>(Cw2, Cw2t, 256, 128);
  transpose_kernel<<<dim3(1, 128), blk, 0, stream>>>(Aw2, Aw2t, 256, 128);

  // one-time E-MLP piecewise-affine tables (parallel: 128 column-blocks)
  emlp_table_kernel<<<dim3(128), dim3(256), 0, stream>>>(Ew1, Eb1, Ew2, Eb2, ets, Atab, Btab);

  // degree counts -> reciprocals; counting sort emitting sorted (own,oth,x) per side
  const size_t cntbytes = (size_t)((char*)(cntc + N) - (char*)cntp);
  hipMemsetAsync(cntp, 0, cntbytes, stream);
  count_kernel<<<dim3((E + 255) / 256), blk, 0, stream>>>(epn, ecn, cntp, cntc, E, N);
  inv_kernel<<<dim3((N + 255) / 256), blk, 0, stream>>>(cntp, cntc, invp, invc, N);
  scan_pair_kernel<<<dim3(2), dim3(1024), 0, stream>>>(cntp, cntc, offp, offc, N);
  const size_t curbytes = (size_t)((char*)(curc + N) - (char*)curp);
  hipMemsetAsync(curp, 0, curbytes, stream);
  scatter_kernel<<<dim3((E + 255) / 256), blk, 0, stream>>>(
      epn, ecn, epi, eci, offp, offc, curp, curc,
      ownp_s, othp_s, xp_s, ownc_s, othc_s, xc_s, E, N);

  const int nblocks = (N + NB - 1) / NB;
  const int eblocks = (E + EB - 1) / EB;

  // h = MLP_V(batch_token) (f32 into d_out) + Z for hop 0
  node_v_kernel<<<dim3(nblocks), blk, 0, stream>>>(
      batch_token, Vw1t, Vb1, Vw2t, Vb2, Pw1t, Cw1t, Zbuf, hbuf, N);

  const size_t accbytes = (size_t)((char*)(accc + (size_t)N * D_DIM) - (char*)accp);
  for (int hop = 0; hop < 3; ++hop) {
    hipMemsetAsync(accp, 0, accbytes, stream);
    edge_side_kernel<<<dim3(eblocks, 2), dim3(1024), 0, stream>>>(
        Zbuf, ownp_s, othp_s, xp_s, ownc_s, othc_s, xc_s, ets, Atab, Btab,
        Pw1t, Pb1, Pw2t, Pb2, Cw1t, Cb1, Cw2t, Cb2, accp, accc, E, N);
    node_a_kernel<<<dim3(nblocks), blk, 0, stream>>>(
        hbuf, accp, accc, invp, invc, pmask, cmask, stok, etok,
        Aw1t, Ab1, Aw2t, Ab2, Pw1t, Cw1t, Zbuf, (hop < 2) ? 1 : 0, hbuf, N);
  }
}